// Round 1
// baseline (271.516 us; speedup 1.0000x reference)
//
#include <hip/hip_runtime.h>

// mPD_loss: B=2048 batches, N=4095 points, POS=N+1=4096 cumsum positions.
// out = sum_b mean_j sum_c | cumsum(delta)[b,c,j] |  where delta is the
// per-position difference of (deformed cart step) - (orig cart step).

#define BATCH 2048
#define NPTS  4095
#define POS   4096
#define T     256
#define CHUNK 16      // POS / T
#define PAD   17      // chunk stride in LDS (17 coprime 32 -> conflict-free)

__global__ void zero_out_kernel(float* out) { out[0] = 0.0f; }

__launch_bounds__(T)
__global__ void mpd_loss_kernel(const float* __restrict__ origin3,
                                const float* __restrict__ sph3,
                                const float* __restrict__ origin2,
                                const float* __restrict__ sph2,
                                const float* __restrict__ def,
                                float* __restrict__ out) {
    __shared__ float dX[T * PAD];
    __shared__ float dY[T * PAD];
    __shared__ float dZ[T * PAD];
    __shared__ float totX[T], totY[T], totZ[T];
    __shared__ float wsum[T / 64];

    const int b = blockIdx.x;
    const int t = threadIdx.x;

    const float* r3  = sph3 + (size_t)b * 3 * NPTS;
    const float* th3 = r3 + NPTS;
    const float* ph3 = th3 + NPTS;
    const float* r2  = sph2 + (size_t)b * 3 * NPTS;
    const float* th2 = r2 + NPTS;
    const float* ph2 = th2 + NPTS;
    const float* d0  = def + (size_t)b * 2 * NPTS;   // theta deformation
    const float* d1  = d0 + NPTS;                    // phi deformation

    // ---- Phase 1: compute per-position deltas, coalesced loads (j = m*T + t)
    #pragma unroll 4
    for (int m = 0; m < CHUNK; ++m) {
        const int j = m * T + t;
        float dx, dy, dz;
        if (j == 0) {
            const float* o3 = origin3 + (size_t)b * 3;
            const float* o2 = origin2 + (size_t)b * 3;
            dx = o3[0] - o2[0];
            dy = o3[1] - o2[1];
            dz = o3[2] - o2[2];
        } else {
            const int n = j - 1;
            const float R3  = r3[n];
            const float Th3 = th3[n] + d0[n];
            const float Ph3 = ph3[n] + d1[n];
            const float R2  = r2[n];
            const float Th2 = th2[n];
            const float Ph2 = ph2[n];
            float s3, c3, sp3, cp3, s2, c2, sp2, cp2;
            __sincosf(Th3, &s3, &c3);
            __sincosf(Ph3, &sp3, &cp3);
            __sincosf(Th2, &s2, &c2);
            __sincosf(Ph2, &sp2, &cp2);
            const float rs3 = R3 * s3;
            const float rs2 = R2 * s2;
            dx = rs3 * cp3 - rs2 * cp2;
            dy = rs3 * sp3 - rs2 * sp2;
            dz = R3 * c3 - R2 * c2;
        }
        const int addr = (j >> 4) * PAD + (j & 15);
        dX[addr] = dx;
        dY[addr] = dy;
        dZ[addr] = dz;
    }
    __syncthreads();

    // ---- Phase 2a: per-thread chunk totals (thread t owns j = 16t .. 16t+15)
    const int base = t * PAD;
    float sx = 0.f, sy = 0.f, sz = 0.f;
    #pragma unroll
    for (int k = 0; k < CHUNK; ++k) {
        sx += dX[base + k];
        sy += dY[base + k];
        sz += dZ[base + k];
    }
    totX[t] = sx; totY[t] = sy; totZ[t] = sz;
    __syncthreads();

    // ---- Phase 2b: inclusive Hillis-Steele scan of chunk totals
    for (int off = 1; off < T; off <<= 1) {
        float vx = 0.f, vy = 0.f, vz = 0.f;
        if (t >= off) { vx = totX[t - off]; vy = totY[t - off]; vz = totZ[t - off]; }
        __syncthreads();
        totX[t] += vx; totY[t] += vy; totZ[t] += vz;
        __syncthreads();
    }
    const float ox = totX[t] - sx;   // exclusive prefix offsets
    const float oy = totY[t] - sy;
    const float oz = totZ[t] - sz;

    // ---- Phase 2c: running prefix + abs accumulation
    float acc = 0.f;
    float px = ox, py = oy, pz = oz;
    #pragma unroll
    for (int k = 0; k < CHUNK; ++k) {
        px += dX[base + k];
        py += dY[base + k];
        pz += dZ[base + k];
        acc += fabsf(px) + fabsf(py) + fabsf(pz);
    }

    // ---- Block reduce acc, one atomic per block
    #pragma unroll
    for (int off = 32; off > 0; off >>= 1) acc += __shfl_down(acc, off, 64);
    if ((t & 63) == 0) wsum[t >> 6] = acc;
    __syncthreads();
    if (t == 0) {
        const float s = wsum[0] + wsum[1] + wsum[2] + wsum[3];
        atomicAdd(out, s * (1.0f / POS));
    }
}

extern "C" void kernel_launch(void* const* d_in, const int* in_sizes, int n_in,
                              void* d_out, int out_size, void* d_ws, size_t ws_size,
                              hipStream_t stream) {
    const float* origin3 = (const float*)d_in[0];
    const float* sph3    = (const float*)d_in[1];
    const float* origin2 = (const float*)d_in[2];
    const float* sph2    = (const float*)d_in[3];
    const float* def     = (const float*)d_in[4];
    float* out = (float*)d_out;

    zero_out_kernel<<<1, 1, 0, stream>>>(out);
    mpd_loss_kernel<<<BATCH, T, 0, stream>>>(origin3, sph3, origin2, sph2, def, out);
}